// Round 11
// baseline (363.873 us; speedup 1.0000x reference)
//
#include <hip/hip_runtime.h>
#include <cstdint>

// ---------------------------------------------------------------------------
// ConvModule: LN -> GEMM(512->1024)+SiLU -> conv K=5 (1024->1024) -> GLU ->
//             BN -> GEMM(512->512).  B=16, T=1024, C=512. fp32 I/O, bf16 MFMA.
// Round 11: conv = 256x128 block (waves 128x64, acc[8][4]), 1 block/CU.
//  - B staged via global_load_lds DMA direct into FRAG-MAJOR LDS (1 KB frag =
//    one dma; lane l -> (n=l&15, koct=l>>4); 4 octet-lanes share one 64B line
//    -> perfectly coalesced; no LDS-write instructions, no relay VGPRs).
//  - B double-buffered (dma hazard), A double-buffered via named-reg relay.
//  - ONE barrier/chunk; the compiler's vmcnt(0) drain before s_barrier IS the
//    dma completion point (issued at chunk start = full-chunk cover).
//  - GLU+BN fused into epilogue: block cols = 64 a-cols + matching 64 g-cols
//    (+512); pair via LDS transpose; writes h2 bf16 directly (glu_bn deleted).
// Lessons: LDS wall is b128 INSTRUCTION count, not bank patterns (R9/R10
// conflict counter ~ inst count); indexed reg arrays spill (R5/R8); direct-
// global frag reads TCP-bound (R4/R6/R7); static LDS >64KB works (R8 123.9KB).
// ---------------------------------------------------------------------------

#define NB    16
#define TT    1024
#define CC    512
#define C2    1024
#define TPAD  1028        // T + 4 pad rows (2 each side) per batch

typedef unsigned short u16;
typedef short bf16x8 __attribute__((ext_vector_type(8)));
typedef float f32x4  __attribute__((ext_vector_type(4)));

__device__ __forceinline__ float bf2f(u16 u) {
  union { unsigned int i; float f; } v; v.i = ((unsigned int)u) << 16; return v.f;
}
__device__ __forceinline__ u16 f2bf(float f) {
  union { float f; unsigned int i; } v; v.f = f;
  unsigned int x = v.i;
  return (u16)((x + 0x7fffu + ((x >> 16) & 1u)) >> 16);  // RNE
}
// async global->LDS DMA, 16B/lane; LDS dest = wave-uniform base + lane*16.
__device__ __forceinline__ void gload16(const u16* g, u16* l) {
  __builtin_amdgcn_global_load_lds(
      (const __attribute__((address_space(1))) unsigned int*)g,
      (__attribute__((address_space(3))) unsigned int*)l, 16, 0, 0);
}

// ---------------------------------------------------------------------------
__global__ __launch_bounds__(256) void prep_k(
    const float* __restrict__ w1, u16* __restrict__ w1b,
    const float* __restrict__ w3, u16* __restrict__ w3b,
    u16* __restrict__ h1p) {
  const int b = blockIdx.x;
  if (b < 512) {
    const int i = (b * 256 + threadIdx.x) * 4;
    float4 v = *(const float4*)(w1 + i);
    u16 o[4] = { f2bf(v.x), f2bf(v.y), f2bf(v.z), f2bf(v.w) };
    *(uint2*)(w1b + i) = *(const uint2*)o;
  } else if (b < 768) {
    const int i = ((b - 512) * 256 + threadIdx.x) * 4;
    float4 v = *(const float4*)(w3 + i);
    u16 o[4] = { f2bf(v.x), f2bf(v.y), f2bf(v.z), f2bf(v.w) };
    *(uint2*)(w3b + i) = *(const uint2*)o;
  } else {
    const int idx = (b - 768) * 256 + threadIdx.x;
    const int bb  = idx >> 9;
    const int rem = idx & 511;
    const int ri  = rem >> 7;
    const int c8  = (rem & 127) * 8;
    const int row = bb * TPAD + (ri < 2 ? ri : 1024 + ri);   // 0,1,1026,1027
    uint4 z = make_uint4(0u, 0u, 0u, 0u);
    *(uint4*)(h1p + (size_t)row * C2 + c8) = z;
  }
}

// ---------------------------------------------------------------------------
// w2 fp32 (K, I, O) -> w2t bf16 (K, O, I)
__global__ void transpose_w2(const float* __restrict__ w2, u16* __restrict__ w2t) {
  __shared__ u16 t[64][65];
  const int k  = blockIdx.z;
  const int i0 = blockIdx.x * 64, o0 = blockIdx.y * 64;
  const int tx = threadIdx.x, ty = threadIdx.y;
  for (int r = ty; r < 64; r += 4)
    t[r][tx] = f2bf(w2[((size_t)(k * C2) + i0 + r) * C2 + o0 + tx]);
  __syncthreads();
  for (int r = ty; r < 64; r += 4)
    w2t[((size_t)(k * C2) + o0 + r) * C2 + i0 + tx] = t[tx][r];
}

// ---------------------------------------------------------------------------
__global__ __launch_bounds__(256) void layernorm_k(
    const float* __restrict__ x, const float* __restrict__ lng,
    const float* __restrict__ lnb, u16* __restrict__ out) {
  const int tok  = blockIdx.x * 4 + (threadIdx.x >> 6);
  const int lane = threadIdx.x & 63;
  const float* xp = x + (size_t)tok * CC + lane * 8;
  float f[8];
  *(float4*)(f)     = *(const float4*)(xp);
  *(float4*)(f + 4) = *(const float4*)(xp + 4);
  float s = 0.f, s2 = 0.f;
#pragma unroll
  for (int j = 0; j < 8; j++) { s += f[j]; s2 += f[j] * f[j]; }
#pragma unroll
  for (int m = 32; m >= 1; m >>= 1) { s += __shfl_xor(s, m, 64); s2 += __shfl_xor(s2, m, 64); }
  const float mu  = s  * (1.f / 512.f);
  const float var = s2 * (1.f / 512.f) - mu * mu;
  const float rs  = rsqrtf(var + 1e-5f);
  u16 ov[8];
#pragma unroll
  for (int j = 0; j < 8; j++) {
    const int c = lane * 8 + j;
    ov[j] = f2bf((f[j] - mu) * rs * lng[c] + lnb[c]);
  }
  *(uint4*)(out + (size_t)tok * CC + lane * 8) = *(const uint4*)ov;
}

// ---------------------------------------------------------------------------
// GEMM out[m,n] = sum_k A[m,k]*Bt[n,k] + bias[n].  128x128 tile, BK=32.
// (R8/R9 version — proven, kept.)
template <int EPI>
__global__ __launch_bounds__(256, 3) void gemm_bt(
    const u16* __restrict__ A, const u16* __restrict__ Bt,
    const float* __restrict__ bias, void* __restrict__ outv,
    const int Kd, const int ldA) {
  __shared__ __align__(16) u16 smem[20480];   // lsA 2x5120 | lsB 2x5120
  const int tid  = threadIdx.x;
  const int m0   = blockIdx.x * 128;
  const int n0   = blockIdx.y * 128;
  const int wave = tid >> 6, lane = tid & 63;
  const int wm = (wave & 1) * 64, wn = (wave >> 1) * 64;
  const int quad = lane >> 4, l16 = lane & 15;
  const int row = tid >> 2;            // 0..63
  const int kc  = (tid & 3) * 8;       // 0/8/16/24
  const int J = Kd >> 5;               // 16

  const u16* Ap0 = A + (size_t)(m0 + row) * ldA + kc;
  const u16* Ap1 = Ap0 + (size_t)64 * ldA;
  const u16* Bp0 = Bt + (size_t)(n0 + row) * Kd + kc;
  const u16* Bp1 = Bp0 + (size_t)64 * Kd;

  f32x4 acc[4][4] = {};
  uint4 rA0 = *(const uint4*)Ap0, rA1 = *(const uint4*)Ap1;
  uint4 rB0 = *(const uint4*)Bp0, rB1 = *(const uint4*)Bp1;
  *(uint4*)(smem + row * 40 + kc)                = rA0;
  *(uint4*)(smem + (64 + row) * 40 + kc)         = rA1;
  *(uint4*)(smem + 10240 + row * 40 + kc)        = rB0;
  *(uint4*)(smem + 10240 + (64 + row) * 40 + kc) = rB1;
  rA0 = *(const uint4*)(Ap0 + 32); rA1 = *(const uint4*)(Ap1 + 32);
  rB0 = *(const uint4*)(Bp0 + 32); rB1 = *(const uint4*)(Bp1 + 32);
  __syncthreads();

#pragma unroll 1
  for (int j = 0; j < J; j++) {
    const u16* curA = smem + (j & 1) * 5120;
    const u16* curB = smem + 10240 + (j & 1) * 5120;
    if (j + 1 < J) {
      u16* nxtA = smem + ((j + 1) & 1) * 5120;
      u16* nxtB = smem + 10240 + ((j + 1) & 1) * 5120;
      *(uint4*)(nxtA + row * 40 + kc)        = rA0;
      *(uint4*)(nxtA + (64 + row) * 40 + kc) = rA1;
      *(uint4*)(nxtB + row * 40 + kc)        = rB0;
      *(uint4*)(nxtB + (64 + row) * 40 + kc) = rB1;
    }
    {
      const int k2 = (j + 2 < J) ? (j + 2) * 32 : 0;
      rA0 = *(const uint4*)(Ap0 + k2); rA1 = *(const uint4*)(Ap1 + k2);
      rB0 = *(const uint4*)(Bp0 + k2); rB1 = *(const uint4*)(Bp1 + k2);
    }
    bf16x8 af[4], bfr[4];
#pragma unroll
    for (int i = 0; i < 4; i++)
      af[i] = *(const bf16x8*)(curA + (wm + i * 16 + l16) * 40 + quad * 8);
#pragma unroll
    for (int i = 0; i < 4; i++)
      bfr[i] = *(const bf16x8*)(curB + (wn + i * 16 + l16) * 40 + quad * 8);
#pragma unroll
    for (int mi = 0; mi < 4; mi++)
#pragma unroll
      for (int ni = 0; ni < 4; ni++)
        acc[mi][ni] = __builtin_amdgcn_mfma_f32_16x16x32_bf16(
            af[mi], bfr[ni], acc[mi][ni], 0, 0, 0);
    __syncthreads();
  }

  float bv[4];
#pragma unroll
  for (int ni = 0; ni < 4; ni++) bv[ni] = bias[n0 + wn + ni * 16 + l16];

  if (EPI == 0) {
    u16* epi = smem + wave * 4608;       // 64 x 72 u16, private
#pragma unroll
    for (int mi = 0; mi < 4; mi++)
#pragma unroll
      for (int ni = 0; ni < 4; ni++)
#pragma unroll
        for (int r = 0; r < 4; r++) {
          float v = acc[mi][ni][r] + bv[ni];
          v = v / (1.f + __expf(-v));    // SiLU
          epi[(mi * 16 + quad * 4 + r) * 72 + ni * 16 + l16] = f2bf(v);
        }
    u16* h1p = (u16*)outv;
#pragma unroll
    for (int p = 0; p < 8; p++) {
      const int rrow = p * 8 + (lane >> 3);
      const int colb = (lane & 7) * 8;
      uint4 v = *(const uint4*)(epi + rrow * 72 + colb);
      const int rr = m0 + wm + rrow;
      const int bb = rr >> 10, tt = rr & 1023;
      *(uint4*)(h1p + (size_t)(bb * TPAD + tt + 2) * C2 + n0 + wn + colb) = v;
    }
  } else {
    float* fepi = (float*)(smem + wave * 4608);   // 2 x (16 x 68) f32
    float* outf = (float*)outv;
#pragma unroll
    for (int mi = 0; mi < 4; mi++) {
      float* fp = fepi + (mi & 1) * 1088;
#pragma unroll
      for (int ni = 0; ni < 4; ni++)
#pragma unroll
        for (int r = 0; r < 4; r++)
          fp[(quad * 4 + r) * 68 + ni * 16 + l16] = acc[mi][ni][r] + bv[ni];
#pragma unroll
      for (int p = 0; p < 4; p++) {
        const int rrow = p * 4 + (lane >> 4);
        const int col  = (lane & 15) * 4;
        float4 v = *(const float4*)(fp + rrow * 68 + col);
        *(float4*)(outf + (size_t)(m0 + wm + mi * 16 + rrow) * CC + n0 + wn + col) = v;
      }
    }
  }
}

// ---------------------------------------------------------------------------
// Fused conv(5-tap) + GLU + BN.  Block 256m x 128c (c<64: a-col n0+c;
// c>=64: g-col n0+448+c).  Waves 128x64.  A: row-major stride-40 dbuf relay.
// B: frag-major dbuf via global_load_lds (frag f = tap*8+nblk, 1KB, lane l ->
// (n=l&15, koct=l>>4)).  One barrier/chunk.  Epilogue: LDS transpose, GLU+BN,
// bf16 h2 out.
__global__ __launch_bounds__(256, 1) void conv5_fused(
    const u16* __restrict__ h1p, const u16* __restrict__ w2t,
    const float* __restrict__ b2, const float* __restrict__ bng,
    const float* __restrict__ bnb, const float* __restrict__ bnm,
    const float* __restrict__ bnv, u16* __restrict__ h2) {
  __shared__ __align__(16) u16 smem[61760];  // A 2x10400 | B 2x20480 @20800
  const int tid = threadIdx.x;
  const int mt  = blockIdx.x;                // 0..63 (256-row tiles)
  const int n0  = blockIdx.y * 64;           // a-col base (g = +512)
  const int bb  = mt >> 2;
  const int t0  = (mt & 3) * 256;
  const size_t arow0 = (size_t)bb * TPAD + t0;
  const int wave = tid >> 6, lane = tid & 63;
  const int wm = (wave & 1) * 128;           // m-half
  const int wn = (wave >> 1) * 64;           // block-col half
  const int quad = lane >> 4, l16 = lane & 15;
  const int row = tid >> 2;                  // 0..63
  const int kc  = (tid & 3) * 8;
  u16* lsB = smem + 20800;

  const u16* Ap0 = h1p + (arow0 + row) * C2 + kc;
  const u16* Ap1 = Ap0 + (size_t)64 * C2;
  const u16* Ap2 = Ap0 + (size_t)128 * C2;
  const u16* Ap3 = Ap0 + (size_t)192 * C2;
  const u16* Ap4 = h1p + (arow0 + 256 + (tid >> 2)) * C2 + (tid & 3) * 8; // tid<16

  // B dma lane term: u16 offset (n-lane)*1024 + koct*8
  const size_t laneterm = (size_t)l16 * 1024 + (size_t)quad * 8;

#define BDMA(Q, I0, DST) {                                                    \
    const int f_ = wave * 10 + (Q);                                           \
    const int tap_ = f_ >> 3, nb_ = f_ & 7;                                   \
    const size_t uni_ = ((size_t)tap_ * 1024 +                                \
        (size_t)(n0 + nb_ * 16 + ((nb_ >= 4) ? 448 : 0))) * 1024 + (I0);      \
    gload16(w2t + uni_ + laneterm, (DST) + f_ * 512); }
#define BDMA_ALL(I0, DST) BDMA(0,I0,DST) BDMA(1,I0,DST) BDMA(2,I0,DST) \
    BDMA(3,I0,DST) BDMA(4,I0,DST) BDMA(5,I0,DST) BDMA(6,I0,DST)        \
    BDMA(7,I0,DST) BDMA(8,I0,DST) BDMA(9,I0,DST)
#define ASTORE(DST) {                                                         \
    *(uint4*)((DST) + row * 40 + kc)         = rA0;                           \
    *(uint4*)((DST) + (64 + row) * 40 + kc)  = rA1;                           \
    *(uint4*)((DST) + (128 + row) * 40 + kc) = rA2;                           \
    *(uint4*)((DST) + (192 + row) * 40 + kc) = rA3;                           \
    if (tid < 16)                                                             \
      *(uint4*)((DST) + (256 + (tid >> 2)) * 40 + (tid & 3) * 8) = rA4; }
#define ALOAD(I0) {                                                           \
    rA0 = *(const uint4*)(Ap0 + (I0)); rA1 = *(const uint4*)(Ap1 + (I0));     \
    rA2 = *(const uint4*)(Ap2 + (I0)); rA3 = *(const uint4*)(Ap3 + (I0));     \
    if (tid < 16) rA4 = *(const uint4*)(Ap4 + (I0)); }

  f32x4 acc[8][4] = {};
  uint4 rA0, rA1, rA2, rA3, rA4;

  // prologue: A(0)->bufA0, dma B(0)->lsB0, A(1)->regs
  ALOAD(0)
  ASTORE(smem)
  BDMA_ALL(0, lsB)
  ALOAD(32)
  __syncthreads();                            // drains dma(0)

#pragma unroll 1
  for (int j = 0; j < 32; j++) {
    if (j + 1 < 32) {
      BDMA_ALL((j + 1) * 32, lsB + ((j + 1) & 1) * 20480)   // B(j+1)
      ASTORE(smem + ((j + 1) & 1) * 10400)                  // A(j+1)
      const int ia = (j + 2 < 32) ? (j + 2) * 32 : 0;
      ALOAD(ia)                                             // A(j+2)
    }
    const u16* curA = smem + (j & 1) * 10400;
    const u16* curB = lsB + (j & 1) * 20480;
#pragma unroll
    for (int k = 0; k < 5; k++) {
      bf16x8 af[8], bfr[4];
#pragma unroll
      for (int i = 0; i < 8; i++)
        af[i] = *(const bf16x8*)(curA + (wm + i * 16 + l16 + k) * 40 + quad * 8);
#pragma unroll
      for (int i = 0; i < 4; i++)
        bfr[i] = *(const bf16x8*)(curB + (k * 8 + (wn >> 4) + i) * 512 + lane * 8);
#pragma unroll
      for (int mi = 0; mi < 8; mi++)
#pragma unroll
        for (int ni = 0; ni < 4; ni++)
          acc[mi][ni] = __builtin_amdgcn_mfma_f32_16x16x32_bf16(
              af[mi], bfr[ni], acc[mi][ni], 0, 0, 0);
    }
    __syncthreads();   // compute(j) done; dma(j+1)/A-writes drained & visible
  }
#undef BDMA
#undef BDMA_ALL
#undef ASTORE
#undef ALOAD

  // ---- fused epilogue: +b2 -> epi LDS -> GLU -> BN -> h2 (bf16) ----
  float bv[4];
#pragma unroll
  for (int ni = 0; ni < 4; ni++) {
    const int c = wn + ni * 16 + l16;
    bv[ni] = b2[n0 + c + ((c >= 64) ? 448 : 0)];
  }
  u16* epi = smem;                       // 256 x 136 u16 = 34816 <= 61760
#pragma unroll
  for (int mi = 0; mi < 8; mi++)
#pragma unroll
    for (int ni = 0; ni < 4; ni++)
#pragma unroll
      for (int r = 0; r < 4; r++)
        epi[(wm + mi * 16 + quad * 4 + r) * 136 + wn + ni * 16 + l16] =
            f2bf(acc[mi][ni][r] + bv[ni]);
  __syncthreads();

  const int col8 = (tid & 7) * 8;        // 0..56 (a-cols)
  const int r0   = tid >> 3;             // 0..31
  float sc[8], off[8];
#pragma unroll
  for (int c = 0; c < 8; c++) {
    const int gc = n0 + col8 + c;
    const float s = bng[gc] * rsqrtf(bnv[gc] + 1e-5f);
    sc[c] = s; off[c] = bnb[gc] - bnm[gc] * s;
  }
  const size_t orow0 = (size_t)bb * TT + t0;
#pragma unroll
  for (int ro = 0; ro < 8; ro++) {
    const int r = r0 + ro * 32;
    uint4 ua = *(const uint4*)(epi + r * 136 + col8);
    uint4 ug = *(const uint4*)(epi + r * 136 + 64 + col8);
    u16 av[8], gv[8], ov[8];
    *(uint4*)av = ua; *(uint4*)gv = ug;
#pragma unroll
    for (int c = 0; c < 8; c++) {
      const float a = bf2f(av[c]);
      const float g = bf2f(gv[c]);
      const float h = a / (1.f + __expf(-g));
      ov[c] = f2bf(h * sc[c] + off[c]);
    }
    *(uint4*)(h2 + (orow0 + r) * CC + n0 + col8) = *(const uint4*)ov;
  }
}

// ---------------------------------------------------------------------------
extern "C" void kernel_launch(void* const* d_in, const int* in_sizes, int n_in,
                              void* d_out, int out_size, void* d_ws, size_t ws_size,
                              hipStream_t stream) {
  const float* x   = (const float*)d_in[0];
  const float* lng = (const float*)d_in[1];
  const float* lnb = (const float*)d_in[2];
  const float* w1  = (const float*)d_in[3];
  const float* b1  = (const float*)d_in[4];
  const float* w2  = (const float*)d_in[5];
  const float* b2  = (const float*)d_in[6];
  const float* bng = (const float*)d_in[7];
  const float* bnb = (const float*)d_in[8];
  const float* bnm = (const float*)d_in[9];
  const float* bnv = (const float*)d_in[10];
  const float* w3  = (const float*)d_in[11];
  const float* b3  = (const float*)d_in[12];

  u16* ws  = (u16*)d_ws;
  u16* hln = ws;                               // 16384*512 (aliases h2)
  u16* h2  = hln;                              // conv output (hln dead by then)
  u16* h1p = ws + 8388608;                     // 16*1028*1024
  u16* w2t = h1p + 16842752;                   // 5*1024*1024
  u16* w1b = w2t + 5242880;                    // 1024*512
  u16* w3b = w1b + 524288;                     // 512*512

  prep_k      <<<800, 256, 0, stream>>>(w1, w1b, w3, w3b, h1p);
  transpose_w2<<<dim3(16, 16, 5), dim3(64, 4), 0, stream>>>(w2, w2t);
  layernorm_k <<<4096, 256, 0, stream>>>(x, lng, lnb, hln);
  gemm_bt<0>  <<<dim3(128, 8), 256, 0, stream>>>(hln, w1b, b1, h1p, 512, 512);
  conv5_fused <<<dim3(64, 8), 256, 0, stream>>>(h1p, w2t, b2, bng, bnb, bnm, bnv, h2);
  gemm_bt<1>  <<<dim3(128, 4), 256, 0, stream>>>(h2, w3b, b3, d_out, 512, 512);
}